// Round 4
// baseline (37.893 us; speedup 1.0000x reference)
//
#include <hip/hip_runtime.h>
#include <hip/hip_cooperative_groups.h>

namespace cg = cooperative_groups;

// Soft-DTW (banded, r1=BIG, R0 finite only at j=0) collapses exactly to the
// diagonal distance sum: out = sum_i sqrt(max(||x_i - y_i||^2, 1e-12)).
// Single cooperative kernel: per-block partials -> grid.sync -> block 0
// reduces and stores. No memset node (round-3 lesson: a 4B memset node costs
// ~40us/replay as fillBufferAligned), no reliance on d_out/d_ws init state.

#define TN 4096
#define DFN 256
#define RPB 16
#define NBLK (TN / RPB)  // 256 blocks, 4 waves each, 4 rows per wave

__global__ __launch_bounds__(256) void sdtw_coop(const float* __restrict__ x,
                                                 const float* __restrict__ y,
                                                 float* __restrict__ partial,
                                                 float* __restrict__ out) {
  const int wave = threadIdx.x >> 6;
  const int lane = threadIdx.x & 63;
  __shared__ float wsum[4];

  const int base = blockIdx.x * RPB + wave * 4;
  float d2[4];
#pragma unroll
  for (int r = 0; r < 4; ++r) {
    const float4 xv =
        reinterpret_cast<const float4*>(x)[(base + r) * (DFN / 4) + lane];
    const float4 yv =
        reinterpret_cast<const float4*>(y)[(base + r) * (DFN / 4) + lane];
    const float a = xv.x - yv.x;
    const float b = xv.y - yv.y;
    const float c = xv.z - yv.z;
    const float d = xv.w - yv.w;
    d2[r] = a * a + b * b + c * c + d * d;
  }

  float acc = 0.0f;
#pragma unroll
  for (int r = 0; r < 4; ++r) {
    float v = d2[r];
#pragma unroll
    for (int s = 32; s >= 1; s >>= 1) v += __shfl_xor(v, s, 64);
    acc += sqrtf(fmaxf(v, 1e-12f));
  }
  if (lane == 0) wsum[wave] = acc;
  __syncthreads();
  if (threadIdx.x == 0)
    partial[blockIdx.x] = (wsum[0] + wsum[1]) + (wsum[2] + wsum[3]);

  cg::this_grid().sync();

  if (blockIdx.x == 0) {
    float v = partial[threadIdx.x];  // 256 partials, 256 threads
#pragma unroll
    for (int s = 32; s >= 1; s >>= 1) v += __shfl_xor(v, s, 64);
    if (lane == 0) wsum[wave] = v;
    __syncthreads();
    if (threadIdx.x == 0)
      out[0] = (wsum[0] + wsum[1]) + (wsum[2] + wsum[3]);
  }
}

extern "C" void kernel_launch(void* const* d_in, const int* in_sizes, int n_in,
                              void* d_out, int out_size, void* d_ws,
                              size_t ws_size, hipStream_t stream) {
  const float* x = (const float*)d_in[0];
  const float* y = (const float*)d_in[1];
  float* partial = (float*)d_ws;  // NBLK floats = 1 KiB scratch
  float* out = (float*)d_out;

  void* args[] = {(void*)&x, (void*)&y, (void*)&partial, (void*)&out};
  hipLaunchCooperativeKernel((void*)sdtw_coop, dim3(NBLK), dim3(256), args, 0,
                             stream);
}

// Round 5
// 13.319 us; speedup vs baseline: 2.8450x; 2.8450x over previous
//
#include <hip/hip_runtime.h>

// Soft-DTW (banded, r1=BIG, R0 finite only at j=0) collapses exactly to the
// diagonal distance sum: out = sum_i sqrt(max(||x_i - y_i||^2, 1e-12)).
//
// Single kernel node. Last-arriving block (device-scope ticket) reduces the
// 256 per-block partials in fixed index order -> bitwise-deterministic.
// Counter is init-agnostic: values >= NBLK (0xAA poison, or the NBLK left by
// a previous call) are CAS-normalized to 0; fresh-zero is already valid.
// Node-cost lessons: memset node +13us (r3), grid.sync +27us (r4) -> 1 kernel.

#define TN 4096
#define DFN 256
#define RPB 16
#define NBLK (TN / RPB)  // 256 blocks, 4 waves, 4 rows/wave

#define AGENT __HIP_MEMORY_SCOPE_AGENT

__global__ __launch_bounds__(256) void sdtw_one(const float* __restrict__ x,
                                                const float* __restrict__ y,
                                                float* __restrict__ partial,
                                                unsigned* __restrict__ cnt,
                                                float* __restrict__ out) {
  const int wave = threadIdx.x >> 6;
  const int lane = threadIdx.x & 63;
  __shared__ float wsum[4];
  __shared__ unsigned ticket;

  // --- init-agnostic counter normalize (thread 0 of every block) ---
  if (threadIdx.x == 0) {
    unsigned v = __hip_atomic_load(cnt, __ATOMIC_RELAXED, AGENT);
    while (v >= NBLK) {
      if (__hip_atomic_compare_exchange_strong(cnt, &v, 0u, __ATOMIC_RELAXED,
                                               __ATOMIC_RELAXED, AGENT))
        break;
      // v reloaded by failed CAS
    }
  }

  // --- per-block diagonal partial: 16 rows ---
  const int base = blockIdx.x * RPB + wave * 4;
  float d2[4];
#pragma unroll
  for (int r = 0; r < 4; ++r) {
    const float4 xv =
        reinterpret_cast<const float4*>(x)[(base + r) * (DFN / 4) + lane];
    const float4 yv =
        reinterpret_cast<const float4*>(y)[(base + r) * (DFN / 4) + lane];
    const float a = xv.x - yv.x;
    const float b = xv.y - yv.y;
    const float c = xv.z - yv.z;
    const float d = xv.w - yv.w;
    d2[r] = a * a + b * b + c * c + d * d;
  }
  float acc = 0.0f;
#pragma unroll
  for (int r = 0; r < 4; ++r) {
    float v = d2[r];
#pragma unroll
    for (int s = 32; s >= 1; s >>= 1) v += __shfl_xor(v, s, 64);
    acc += sqrtf(fmaxf(v, 1e-12f));
  }
  if (lane == 0) wsum[wave] = acc;
  __syncthreads();

  // --- publish partial, take ticket (release), detect last (acquire) ---
  if (threadIdx.x == 0) {
    const float p = (wsum[0] + wsum[1]) + (wsum[2] + wsum[3]);
    __hip_atomic_store(&partial[blockIdx.x], p, __ATOMIC_RELAXED, AGENT);
    ticket = __hip_atomic_fetch_add(cnt, 1u, __ATOMIC_ACQ_REL, AGENT);
  }
  __syncthreads();

  if (ticket == NBLK - 1) {  // last block: all partials visible
    float v = __hip_atomic_load(&partial[threadIdx.x], __ATOMIC_RELAXED, AGENT);
#pragma unroll
    for (int s = 32; s >= 1; s >>= 1) v += __shfl_xor(v, s, 64);
    if (lane == 0) wsum[wave] = v;
    __syncthreads();
    if (threadIdx.x == 0)
      out[0] = (wsum[0] + wsum[1]) + (wsum[2] + wsum[3]);
  }
}

extern "C" void kernel_launch(void* const* d_in, const int* in_sizes, int n_in,
                              void* d_out, int out_size, void* d_ws,
                              size_t ws_size, hipStream_t stream) {
  const float* x = (const float*)d_in[0];
  const float* y = (const float*)d_in[1];
  float* partial = (float*)d_ws;                 // NBLK floats
  unsigned* cnt = (unsigned*)((float*)d_ws + NBLK);  // 1 u32 after partials
  float* out = (float*)d_out;

  sdtw_one<<<NBLK, 256, 0, stream>>>(x, y, partial, cnt, out);
}